// Round 2
// baseline (753.530 us; speedup 1.0000x reference)
//
#include <hip/hip_runtime.h>
#include <stdint.h>
#include <stddef.h>

// ---------------------------------------------------------------------------
// out[b,t,f] = x @ (w + 2.0 * lora_a @ lora_b)     (LoRA folded into weight)
// M = 8192 (B*T), K = 2048 (D), N = 8192 (F). fp32 in/out, bf16 MFMA compute.
// R2: vectorized pre-passes + 32x32x16 MFMA GEMM.
// ---------------------------------------------------------------------------

typedef __bf16 bf16;
typedef __bf16 bf16x8 __attribute__((ext_vector_type(8)));
typedef float  f32x16 __attribute__((ext_vector_type(16)));

#define M_DIM 8192
#define N_DIM 8192
#define K_DIM 2048
#define LRANK 16
#define LSCALE 2.0f

#define BM 128
#define BN 128
#define BK 64

typedef __attribute__((address_space(1))) void* as1_void;
typedef __attribute__((address_space(3))) void* as3_void;

__device__ __forceinline__ void gload_lds16(const void* g, void* l) {
    __builtin_amdgcn_global_load_lds((as1_void)(g), (as3_void)(l), 16, 0, 0);
}

// ---------------------------------------------------------------------------
// Kernel 1: x fp32 -> bf16. 8 elems/thread: 2x float4 load, 1x 16-B store.
// ---------------------------------------------------------------------------
__global__ void convert_x_kernel(const float* __restrict__ x,
                                 bf16* __restrict__ xb) {
    size_t i = (size_t)(blockIdx.x * blockDim.x + threadIdx.x) * 8;
    float4 v0 = *(const float4*)(x + i);
    float4 v1 = *(const float4*)(x + i + 4);
    bf16x8 o;
    o[0] = (bf16)v0.x; o[1] = (bf16)v0.y; o[2] = (bf16)v0.z; o[3] = (bf16)v0.w;
    o[4] = (bf16)v1.x; o[5] = (bf16)v1.y; o[6] = (bf16)v1.z; o[7] = (bf16)v1.w;
    *(bf16x8*)(xb + i) = o;
}

// ---------------------------------------------------------------------------
// Kernel 2: Wt[n][k] = bf16( w[k][n] + 2.0 * sum_L a[k][L]*b[L][n] )
// 64x64 tile transpose through LDS. float4 global loads, bf16x8 stores.
// Thread t: kl0=(t&7)*8 (8 consecutive k -> one 16-B store), nl=(t>>3)(+32).
// at[] scalar reads: 8 lanes/wave share each address (broadcast) and the 8
// distinct rows land on 4 bank-pairs -> 2-way aliasing = free (m136).
// ---------------------------------------------------------------------------
__global__ void fold_transpose_kernel(const float* __restrict__ w,   // [K][N]
                                      const float* __restrict__ la,  // [K][16]
                                      const float* __restrict__ lb,  // [16][N]
                                      bf16* __restrict__ wt) {       // [N][K]
    __shared__ float tile[64][65];   // 65: transpose-read 2-way max
    __shared__ float at[64][17];     // 17: row-spread for broadcast reads
    __shared__ float bt[16][64];

    const int k0 = blockIdx.x * 64;
    const int n0 = blockIdx.y * 64;
    const int t  = threadIdx.x;      // 256 threads

    // w tile: 64 rows x 64 cols, float4 per thread x4 passes (coalesced)
    {
        const int r = t >> 4;          // 0..15
        const int c4 = (t & 15) * 4;
        #pragma unroll
        for (int p = 0; p < 4; ++p) {
            const int row = r + p * 16;
            float4 v = *(const float4*)(w + (size_t)(k0 + row) * N_DIM + n0 + c4);
            tile[row][c4 + 0] = v.x; tile[row][c4 + 1] = v.y;
            tile[row][c4 + 2] = v.z; tile[row][c4 + 3] = v.w;
        }
    }
    // a rows: 64 x 16 floats, one float4 per thread (coalesced)
    {
        const int row = t >> 2, c4 = (t & 3) * 4;
        float4 v = *(const float4*)(la + (size_t)(k0 + row) * LRANK + c4);
        at[row][c4 + 0] = v.x; at[row][c4 + 1] = v.y;
        at[row][c4 + 2] = v.z; at[row][c4 + 3] = v.w;
    }
    // b rows: 16 x 64 floats, one float4 per thread (coalesced)
    {
        const int row = t >> 4, c4 = (t & 15) * 4;
        float4 v = *(const float4*)(lb + (size_t)row * N_DIM + n0 + c4);
        bt[row][c4 + 0] = v.x; bt[row][c4 + 1] = v.y;
        bt[row][c4 + 2] = v.z; bt[row][c4 + 3] = v.w;
    }
    __syncthreads();

    const int kl0 = (t & 7) * 8;
    const int nlb = t >> 3;            // 0..31

    // a rows for this thread's 8 k values -> registers (shared across h)
    float areg[8][LRANK];
    #pragma unroll
    for (int j = 0; j < 8; ++j)
        #pragma unroll
        for (int L = 0; L < LRANK; ++L)
            areg[j][L] = at[kl0 + j][L];

    #pragma unroll
    for (int h = 0; h < 2; ++h) {
        const int nl = nlb + h * 32;
        float bcol[LRANK];
        #pragma unroll
        for (int L = 0; L < LRANK; ++L) bcol[L] = bt[L][nl];
        bf16x8 o;
        #pragma unroll
        for (int j = 0; j < 8; ++j) {
            float delta = 0.f;
            #pragma unroll
            for (int L = 0; L < LRANK; ++L) delta += areg[j][L] * bcol[L];
            o[j] = (bf16)(tile[kl0 + j][nl] + LSCALE * delta);
        }
        *(bf16x8*)(wt + (size_t)(n0 + nl) * K_DIM + k0 + kl0) = o;
    }
}

// ---------------------------------------------------------------------------
// Kernel 3: C = A * Bt^T, bf16 in, fp32 out. 128x128 tile, BK=64, 4 waves
// each 64x64 via 2x2 of mfma_f32_32x32x16_bf16 (half the MFMA issue slots
// of 16x16x32 at ~15% higher pipe rate). Staging + XOR swizzle unchanged
// from R1 (measured 0 bank conflicts).
// A/B operand: elem[m/n = lane&31][k = (lane>>5)*8 + j]
// C/D:         col = lane&31, row = (reg&3) + 8*(reg>>2) + 4*(lane>>5)
// ---------------------------------------------------------------------------
__global__ __launch_bounds__(256)
void gemm_bf16_kernel(const bf16* __restrict__ A,   // [M][K]
                      const bf16* __restrict__ Bt,  // [N][K]
                      float* __restrict__ C) {      // [M][N]
    __shared__ __align__(16) bf16 As[BM * BK];
    __shared__ __align__(16) bf16 Bs[BN * BK];

    const int t    = threadIdx.x;
    const int lane = t & 63;
    const int wave = t >> 6;            // 0..3
    const int wm   = (wave >> 1) * 64;
    const int wn   = (wave & 1) * 64;

    const int n0 = blockIdx.x * BN;
    const int m0 = blockIdx.y * BM;

    // staging: 4 x 16B/thread per operand covers 16 KB.
    // physical chunk cp at (row, cp) holds logical k-chunk cl = cp ^ (row&7)
    int rowS[4], clS[4];
    #pragma unroll
    for (int j = 0; j < 4; ++j) {
        int p   = j * 4096 + t * 16;
        int row = p >> 7;
        int cp  = (p >> 4) & 7;
        rowS[j] = row;
        clS[j]  = cp ^ (row & 7);
    }
    const bf16* aBase = A  + (size_t)m0 * K_DIM;
    const bf16* bBase = Bt + (size_t)n0 * K_DIM;

    // fragment LDS offsets: 4 k-steps (k=16 each) x 2 row-tiles
    int offA[4][2], offB[4][2];
    #pragma unroll
    for (int s = 0; s < 4; ++s) {
        const int cl = s * 2 + (lane >> 5);
        #pragma unroll
        for (int i = 0; i < 2; ++i) {
            const int rowa = wm + i * 32 + (lane & 31);
            const int rowb = wn + i * 32 + (lane & 31);
            offA[s][i] = rowa * 64 + ((cl ^ (rowa & 7)) * 8);
            offB[s][i] = rowb * 64 + ((cl ^ (rowb & 7)) * 8);
        }
    }

    f32x16 acc[2][2] = {};

    for (int kt = 0; kt < K_DIM / BK; ++kt) {
        const int k0 = kt * BK;
        #pragma unroll
        for (int j = 0; j < 4; ++j) {
            gload_lds16(aBase + (size_t)rowS[j] * K_DIM + k0 + clS[j] * 8,
                        As + j * 2048 + t * 8);
            gload_lds16(bBase + (size_t)rowS[j] * K_DIM + k0 + clS[j] * 8,
                        Bs + j * 2048 + t * 8);
        }
        __syncthreads();

        #pragma unroll
        for (int s = 0; s < 4; ++s) {
            bf16x8 af[2], bfr[2];
            #pragma unroll
            for (int i = 0; i < 2; ++i) af[i]  = *(const bf16x8*)(As + offA[s][i]);
            #pragma unroll
            for (int i = 0; i < 2; ++i) bfr[i] = *(const bf16x8*)(Bs + offB[s][i]);
            #pragma unroll
            for (int mi = 0; mi < 2; ++mi)
                #pragma unroll
                for (int ni = 0; ni < 2; ++ni)
                    acc[mi][ni] = __builtin_amdgcn_mfma_f32_32x32x16_bf16(
                        af[mi], bfr[ni], acc[mi][ni], 0, 0, 0);
        }
        __syncthreads();
    }

    // epilogue
    const int cc = lane & 31;
    const int rb = 4 * (lane >> 5);
    float* cBase = C + (size_t)(m0 + wm + rb) * N_DIM + (n0 + wn + cc);
    #pragma unroll
    for (int mi = 0; mi < 2; ++mi)
        #pragma unroll
        for (int ni = 0; ni < 2; ++ni)
            #pragma unroll
            for (int r = 0; r < 16; ++r) {
                const int rowo = mi * 32 + (r & 3) + 8 * (r >> 2);
                cBase[(size_t)rowo * N_DIM + ni * 32] = acc[mi][ni][r];
            }
}

// ---------------------------------------------------------------------------
extern "C" void kernel_launch(void* const* d_in, const int* in_sizes, int n_in,
                              void* d_out, int out_size, void* d_ws, size_t ws_size,
                              hipStream_t stream) {
    const float* x  = (const float*)d_in[0];   // [8192, 2048]
    const float* w  = (const float*)d_in[1];   // [2048, 8192]
    const float* la = (const float*)d_in[2];   // [2048, 16]
    const float* lb = (const float*)d_in[3];   // [16, 8192]
    float* out = (float*)d_out;                // [8192, 8192]

    bf16* xb = (bf16*)d_ws;                                        // 32 MB
    bf16* wt = (bf16*)((char*)d_ws + (size_t)M_DIM * K_DIM * 2);   // 32 MB

    convert_x_kernel<<<M_DIM * K_DIM / 8 / 256, 256, 0, stream>>>(x, xb);
    fold_transpose_kernel<<<dim3(K_DIM / 64, N_DIM / 64), 256, 0, stream>>>(w, la, lb, wt);
    gemm_bf16_kernel<<<dim3(N_DIM / BN, M_DIM / BM), 256, 0, stream>>>(xb, wt, out);
}